// Round 1
// baseline (199.625 us; speedup 1.0000x reference)
//
#include <hip/hip_runtime.h>

#define NUM_SEG 32
#define MUL 128
#define D 3
#define NUM_PATHS 64
#define ROW (NUM_SEG * MUL * D)   // 12288 floats per batch row

__global__ __launch_bounds__(256) void ftp_kernel(
    const float* __restrict__ x0, const float* __restrict__ x1,
    const float* __restrict__ coeff, const int* __restrict__ idx0,
    const int* __restrict__ idx1, const int* __restrict__ idx2,
    float* __restrict__ out)
{
    const int b   = blockIdx.x;
    const int tid = threadIdx.x;

    __shared__ float s_x0[ROW];                            // 48 KB: full x0 row
    __shared__ float s_m[NUM_PATHS][D][D];                 // m[p][i][k]
    __shared__ int   s_seg0[NUM_PATHS];                    // idx0 per path
    __shared__ unsigned char s_plist[NUM_SEG][NUM_PATHS];  // per-segment path lists
    __shared__ int   s_cnt[NUM_SEG];

    if (tid < NUM_SEG) s_cnt[tid] = 0;

    // Stage x0 row into LDS: 3072 float4 / 256 threads = 12 per thread, coalesced.
    const float4* __restrict__ x0v = (const float4*)(x0 + (size_t)b * ROW);
    float4* s_x0v = (float4*)s_x0;
    #pragma unroll
    for (int i = 0; i < ROW / 4 / 256; ++i)
        s_x0v[i * 256 + tid] = x0v[i * 256 + tid];

    __syncthreads();   // s_cnt zeroed before atomics below

    if (tid < NUM_PATHS) {
        const int p  = tid;
        const int i1 = idx1[p];
        s_seg0[p]    = idx0[p];
        const int s2 = idx2[p];
        const int pos = atomicAdd(&s_cnt[s2], 1);
        s_plist[s2][pos] = (unsigned char)p;

        const float* x1row = x1 + (size_t)b * (NUM_SEG * D) + i1 * D;
        const float xj0 = x1row[0], xj1 = x1row[1], xj2 = x1row[2];
        const float* cf = coeff + p * 27;   // coeff[p][i][j][k]
        #pragma unroll
        for (int i = 0; i < D; ++i) {
            #pragma unroll
            for (int k = 0; k < D; ++k) {
                s_m[p][i][k] = xj0 * cf[i * 9 + 0 + k]
                             + xj1 * cf[i * 9 + 3 + k]
                             + xj2 * cf[i * 9 + 6 + k];
            }
        }
    }
    __syncthreads();   // x0 staged, m + path lists built

    // Thread owns u = tid&127; waves have uniform segment -> uniform control flow.
    const int u  = tid & (MUL - 1);
    const int sg = tid >> 7;               // 0 or 1
    float* outrow = out + (size_t)b * ROW;

    for (int s = sg; s < NUM_SEG; s += 2) {
        float acc0 = 0.f, acc1 = 0.f, acc2 = 0.f;
        const int n = s_cnt[s];
        for (int t = 0; t < n; ++t) {
            const int p = s_plist[s][t];
            const float* xs = &s_x0[s_seg0[p] * (MUL * D) + u * D];
            const float a0 = xs[0], a1 = xs[1], a2 = xs[2];
            acc0 += a0 * s_m[p][0][0] + a1 * s_m[p][1][0] + a2 * s_m[p][2][0];
            acc1 += a0 * s_m[p][0][1] + a1 * s_m[p][1][1] + a2 * s_m[p][2][1];
            acc2 += a0 * s_m[p][0][2] + a1 * s_m[p][1][2] + a2 * s_m[p][2][2];
        }
        float* o = outrow + s * (MUL * D) + u * D;
        o[0] = acc0; o[1] = acc1; o[2] = acc2;
    }
}

extern "C" void kernel_launch(void* const* d_in, const int* in_sizes, int n_in,
                              void* d_out, int out_size, void* d_ws, size_t ws_size,
                              hipStream_t stream) {
    const float* x0    = (const float*)d_in[0];
    const float* x1    = (const float*)d_in[1];
    const float* coeff = (const float*)d_in[2];
    const int*   idx0  = (const int*)d_in[3];
    const int*   idx1  = (const int*)d_in[4];
    const int*   idx2  = (const int*)d_in[5];
    float* out = (float*)d_out;

    const int B = in_sizes[0] / ROW;
    ftp_kernel<<<B, 256, 0, stream>>>(x0, x1, coeff, idx0, idx1, idx2, out);
}